// Round 1
// baseline (414.348 us; speedup 1.0000x reference)
//
#include <hip/hip_runtime.h>

// RefLocal: 5x5 windowed dot-product attention, fp32.
// B=8 H=96 W=96 C=192 V=96.
// R7 = R6 + horizontal query-pairing (2 queries x 4 channels per thread):
//  - R6 counters: LDS-pipe-bound (window ds_read_b128 ~50us busy of 81us,
//    HBM 16% peak, VALU 23%). Window reads were 0.25 FMA/byte with each
//    thread privately re-reading its 25 halo pixels.
//  - Each thread now owns query cols (2pc, 2pc+1) in row pr and a 4-channel
//    slice. The 5x6 window-row union is read once (6 x b128 per row) and
//    feeds both queries: 480B instead of 800B LDS reads per thread per
//    chunk (x0.6), same 200 FMA.
//  - Cross-slice logit reduction: LDS round-trip (+2 barriers) replaced by
//    __shfl_xor butterfly over lane bits 0..2 (slice lanes are adjacent).
//  - Out-stage stride 33 -> 36: float4s 16B-aligned (real b128), quads
//    still spread via (px + slice) phase.

#define BATCH 8
#define HH 96
#define WW 96
#define CH 192
#define VV 96
#define KS 5
#define PAD 2
#define TH 8
#define TW 8
#define HT (TH + 2 * PAD) // 12
#define WT (TW + 2 * PAD) // 12
#define NPIX (HT * WT)    // 144
#define CHUNK 32          // channels staged per iteration
#define SPX 36            // LDS floats per halo pixel (32 data + 4 pad)
#define SO 36             // out-stage stride (16B-aligned float4)
#define SOFF (NPIX * SPX) // 5184: out-stage base (disjoint from halo)
#define SSZ (SOFF + 64 * SO) // 7488 floats = 29952 B

#define DOT4(m, k) \
  ((m).x * (k).x + (m).y * (k).y + (m).z * (k).z + (m).w * (k).w)

__global__ __launch_bounds__(256, 3) void reflocal_kernel(
    const float* __restrict__ qry, const float* __restrict__ key,
    const float* __restrict__ val, float* __restrict__ out) {
  // XCD swizzle: blockIdx round-robins across 8 XCDs; one image per XCD.
  int braw = blockIdx.x;
  int L = (braw & 7) * 144 + (braw >> 3); // gridDim.x == 1152
  int bb = L / 144;
  int t2 = L - bb * 144;
  int tyy = t2 / 12;
  int txx = t2 - tyy * 12;
  int h0 = tyy * TH, w0 = txx * TW;

  int tid = threadIdx.x;
  int s4 = (tid & 7) * 4;   // 4-channel sub-slice within the 32-ch chunk
  int pr = (tid >> 3) >> 2; // query row 0..7
  int pc = (tid >> 3) & 3;  // query col-pair 0..3
  int qx0 = 2 * pc;         // first query col (halo col of window j=0)

  __shared__ float s[SSZ];

  // ---- precomputed staging bookkeeping (identical to R6) ----
  // thread handles quads t = tid + 256*r, r=0..4; t = px*8 + q, q == tid&7.
  int pidx[5]; // global pixel linear index, -1 = OOB (store zeros), -2 = skip
  int ldst[5]; // LDS float offset
#pragma unroll
  for (int r = 0; r < 5; ++r) {
    int px = (tid >> 3) + 32 * r;
    if (px < NPIX) {
      int ry = px / WT, rx = px - ry * WT;
      int hh = h0 - PAD + ry, ww = w0 - PAD + rx;
      pidx[r] = ((unsigned)hh < HH && (unsigned)ww < WW)
                    ? (bb * HH + hh) * WW + ww
                    : -1;
      ldst[r] = px * SPX + s4;
    } else {
      pidx[r] = -2;
      ldst[r] = 0;
    }
  }

  float lg0[25], lg1[25];
#pragma unroll
  for (int o = 0; o < 25; ++o) { lg0[o] = 0.f; lg1[o] = 0.f; }

  const float* qb0 =
      qry + (size_t)((bb * HH + h0 + pr) * WW + w0 + qx0) * CH;
  const float* qb1 = qb0 + CH; // adjacent column pixel

  // ---- Phase 1: partial logits, C in chunks of 32 ----
  float4 pf[5];
#pragma unroll
  for (int r = 0; r < 5; ++r) { // prefetch chunk 0
    float4 v4 = make_float4(0.f, 0.f, 0.f, 0.f);
    if (pidx[r] >= 0)
      v4 = *(const float4*)(key + (size_t)pidx[r] * CH + s4);
    pf[r] = v4;
  }

  for (int c0 = 0; c0 < CH; c0 += CHUNK) {
    __syncthreads();
#pragma unroll
    for (int r = 0; r < 5; ++r)
      if (pidx[r] != -2) *(float4*)(&s[ldst[r]]) = pf[r];
    __syncthreads();
    if (c0 + CHUNK < CH) { // prefetch next chunk; waitcnt lands next iter
      int cn = c0 + CHUNK + s4;
#pragma unroll
      for (int r = 0; r < 5; ++r) {
        float4 v4 = make_float4(0.f, 0.f, 0.f, 0.f);
        if (pidx[r] >= 0)
          v4 = *(const float4*)(key + (size_t)pidx[r] * CH + cn);
        pf[r] = v4;
      }
    }

    float4 m0 = *(const float4*)(qb0 + c0 + s4);
    float4 m1 = *(const float4*)(qb1 + c0 + s4);
#pragma unroll
    for (int i = 0; i < KS; ++i) {
      const float* sp = &s[((pr + i) * WT + qx0) * SPX + s4];
      float4 kr[6];
#pragma unroll
      for (int u = 0; u < 6; ++u) kr[u] = *(const float4*)(sp + u * SPX);
#pragma unroll
      for (int j = 0; j < KS; ++j) {
        lg0[i * 5 + j] += DOT4(m0, kr[j]);
        lg1[i * 5 + j] += DOT4(m1, kr[j + 1]);
      }
    }
  }

  // ---- cross-slice logit reduction: in-wave butterfly over lane bits 0..2
  // (slice lanes are adjacent; all 8 lanes of a pair end with the full sum)
#pragma unroll
  for (int o = 0; o < 25; ++o) {
    lg0[o] += __shfl_xor(lg0[o], 1);
    lg0[o] += __shfl_xor(lg0[o], 2);
    lg0[o] += __shfl_xor(lg0[o], 4);
    lg1[o] += __shfl_xor(lg1[o], 1);
    lg1[o] += __shfl_xor(lg1[o], 2);
    lg1[o] += __shfl_xor(lg1[o], 4);
  }

  // prefetch V chunk 0 (overlaps softmax math below)
#pragma unroll
  for (int r = 0; r < 5; ++r) {
    float4 v4 = make_float4(0.f, 0.f, 0.f, 0.f);
    if (pidx[r] >= 0)
      v4 = *(const float4*)(val + (size_t)pidx[r] * VV + s4);
    pf[r] = v4;
  }

  // ---- softmax over 25 (zero halo contributed logit 0 = TF SAME pad) ----
  {
    float mx = lg0[0];
#pragma unroll
    for (int o = 1; o < 25; ++o) mx = fmaxf(mx, lg0[o]);
    float sum = 0.f;
#pragma unroll
    for (int o = 0; o < 25; ++o) {
      lg0[o] = __expf(lg0[o] - mx);
      sum += lg0[o];
    }
    float inv = 1.f / sum;
#pragma unroll
    for (int o = 0; o < 25; ++o) lg0[o] *= inv;
  }
  {
    float mx = lg1[0];
#pragma unroll
    for (int o = 1; o < 25; ++o) mx = fmaxf(mx, lg1[o]);
    float sum = 0.f;
#pragma unroll
    for (int o = 0; o < 25; ++o) {
      lg1[o] = __expf(lg1[o] - mx);
      sum += lg1[o];
    }
    float inv = 1.f / sum;
#pragma unroll
    for (int o = 0; o < 25; ++o) lg1[o] *= inv;
  }

  // ---- Phase 2: values, V in chunks of 32; LDS-staged coalesced write ----
  for (int v0 = 0; v0 < VV; v0 += CHUNK) {
    __syncthreads(); // also covers: phase-1 tail reads done before overwrite
#pragma unroll
    for (int r = 0; r < 5; ++r)
      if (pidx[r] != -2) *(float4*)(&s[ldst[r]]) = pf[r];
    __syncthreads();
    if (v0 + CHUNK < VV) {
      int vn = v0 + CHUNK + s4;
#pragma unroll
      for (int r = 0; r < 5; ++r) {
        float4 v4 = make_float4(0.f, 0.f, 0.f, 0.f);
        if (pidx[r] >= 0)
          v4 = *(const float4*)(val + (size_t)pidx[r] * VV + vn);
        pf[r] = v4;
      }
    }

    float4 a0 = make_float4(0.f, 0.f, 0.f, 0.f);
    float4 a1 = make_float4(0.f, 0.f, 0.f, 0.f);
#pragma unroll
    for (int i = 0; i < KS; ++i) {
      const float* sp = &s[((pr + i) * WT + qx0) * SPX + s4];
      float4 vr[6];
#pragma unroll
      for (int u = 0; u < 6; ++u) vr[u] = *(const float4*)(sp + u * SPX);
#pragma unroll
      for (int j = 0; j < KS; ++j) {
        float w0a = lg0[i * 5 + j];
        float w1a = lg1[i * 5 + j];
        a0.x += w0a * vr[j].x;     a0.y += w0a * vr[j].y;
        a0.z += w0a * vr[j].z;     a0.w += w0a * vr[j].w;
        a1.x += w1a * vr[j + 1].x; a1.y += w1a * vr[j + 1].y;
        a1.z += w1a * vr[j + 1].z; a1.w += w1a * vr[j + 1].w;
      }
    }
    // stage into out-region (disjoint from halo; no barrier needed before)
    int px0 = pr * 8 + qx0;
    *(float4*)(&s[SOFF + px0 * SO + s4]) = a0;
    *(float4*)(&s[SOFF + (px0 + 1) * SO + s4]) = a1;
    __syncthreads();

    // coalesced write: 8 consecutive lanes cover 128 contiguous bytes
    for (int t = tid; t < 64 * (CHUNK / 4); t += 256) {
      int px = t >> 3, c4 = (t & 7) * 4;
      int pty = px >> 3, ptx = px & 7;
      float4 v4 = *(const float4*)(&s[SOFF + px * SO + c4]);
      *(float4*)(out + (size_t)((bb * HH + h0 + pty) * WW + w0 + ptx) * VV +
                 v0 + c4) = v4;
    }
  }
}

extern "C" void kernel_launch(void* const* d_in, const int* in_sizes, int n_in,
                              void* d_out, int out_size, void* d_ws,
                              size_t ws_size, hipStream_t stream) {
  const float* qry = (const float*)d_in[0]; // main [B,H,W,C]
  const float* key = (const float*)d_in[1]; // ref  [B,H,W,C]
  const float* val = (const float*)d_in[2]; // ref_value [B,H,W,V]
  float* out = (float*)d_out;               // [B,H,W,V]

  dim3 grid(BATCH * (HH / TH) * (WW / TW)); // 1152
  dim3 block(256);
  reflocal_kernel<<<grid, block, 0, stream>>>(qry, key, val, out);
}

// Round 2
// 210.467 us; speedup vs baseline: 1.9687x; 1.9687x over previous
//
#include <hip/hip_runtime.h>

// RefLocal: 5x5 windowed dot-product attention, fp32.
// B=8 H=96 W=96 C=192 V=96.
// R8 = R7 with the register cap reverted.
//  - R7 post-mortem: __launch_bounds__(256,3) forces VGPR<=128 (occupancy
//    steps at 64/128/256), the paired kernel needs ~150 live regs ->
//    compiler spilled lg arrays to scratch (VGPR 84, +450MB FETCH/WRITE
//    round-trip, 311us). The pairing itself was never measured.
//  - (256,2): 256-VGPR budget, no spill. 2 blocks/CU worst case; LDS pipe
//    is the throughput limiter (R6 analysis), 8 waves + ILP-6 window loads
//    should keep it busy.
//  - Horizontal query-pairing (2 queries x 4 ch per thread): 5x6 window-row
//    union read once (6 b128), feeds both queries: 480B LDS read per
//    thread per chunk vs 800B unpaired (x0.6), same 200 FMA.
//  - Cross-slice logit reduction via __shfl_xor butterfly (lane bits 0..2).

#define BATCH 8
#define HH 96
#define WW 96
#define CH 192
#define VV 96
#define KS 5
#define PAD 2
#define TH 8
#define TW 8
#define HT (TH + 2 * PAD) // 12
#define WT (TW + 2 * PAD) // 12
#define NPIX (HT * WT)    // 144
#define CHUNK 32          // channels staged per iteration
#define SPX 36            // LDS floats per halo pixel (32 data + 4 pad)
#define SO 36             // out-stage stride (16B-aligned float4)
#define SOFF (NPIX * SPX) // 5184: out-stage base (disjoint from halo)
#define SSZ (SOFF + 64 * SO) // 7488 floats = 29952 B

#define DOT4(m, k) \
  ((m).x * (k).x + (m).y * (k).y + (m).z * (k).z + (m).w * (k).w)

__global__ __launch_bounds__(256, 2) void reflocal_kernel(
    const float* __restrict__ qry, const float* __restrict__ key,
    const float* __restrict__ val, float* __restrict__ out) {
  // XCD swizzle: blockIdx round-robins across 8 XCDs; one image per XCD.
  int braw = blockIdx.x;
  int L = (braw & 7) * 144 + (braw >> 3); // gridDim.x == 1152
  int bb = L / 144;
  int t2 = L - bb * 144;
  int tyy = t2 / 12;
  int txx = t2 - tyy * 12;
  int h0 = tyy * TH, w0 = txx * TW;

  int tid = threadIdx.x;
  int s4 = (tid & 7) * 4;   // 4-channel sub-slice within the 32-ch chunk
  int pr = (tid >> 3) >> 2; // query row 0..7
  int pc = (tid >> 3) & 3;  // query col-pair 0..3
  int qx0 = 2 * pc;         // first query col (halo col of window j=0)

  __shared__ float s[SSZ];

  // ---- precomputed staging bookkeeping ----
  // thread handles quads t = tid + 256*r, r=0..4; t = px*8 + q, q == tid&7.
  int pidx[5]; // global pixel linear index, -1 = OOB (store zeros), -2 = skip
  int ldst[5]; // LDS float offset
#pragma unroll
  for (int r = 0; r < 5; ++r) {
    int px = (tid >> 3) + 32 * r;
    if (px < NPIX) {
      int ry = px / WT, rx = px - ry * WT;
      int hh = h0 - PAD + ry, ww = w0 - PAD + rx;
      pidx[r] = ((unsigned)hh < HH && (unsigned)ww < WW)
                    ? (bb * HH + hh) * WW + ww
                    : -1;
      ldst[r] = px * SPX + s4;
    } else {
      pidx[r] = -2;
      ldst[r] = 0;
    }
  }

  float lg0[25], lg1[25];
#pragma unroll
  for (int o = 0; o < 25; ++o) { lg0[o] = 0.f; lg1[o] = 0.f; }

  const float* qb0 =
      qry + (size_t)((bb * HH + h0 + pr) * WW + w0 + qx0) * CH;
  const float* qb1 = qb0 + CH; // adjacent column pixel

  // ---- Phase 1: partial logits, C in chunks of 32 ----
  float4 pf[5];
#pragma unroll
  for (int r = 0; r < 5; ++r) { // prefetch chunk 0
    float4 v4 = make_float4(0.f, 0.f, 0.f, 0.f);
    if (pidx[r] >= 0)
      v4 = *(const float4*)(key + (size_t)pidx[r] * CH + s4);
    pf[r] = v4;
  }

  for (int c0 = 0; c0 < CH; c0 += CHUNK) {
    __syncthreads();
#pragma unroll
    for (int r = 0; r < 5; ++r)
      if (pidx[r] != -2) *(float4*)(&s[ldst[r]]) = pf[r];
    __syncthreads();
    if (c0 + CHUNK < CH) { // prefetch next chunk; waitcnt lands next iter
      int cn = c0 + CHUNK + s4;
#pragma unroll
      for (int r = 0; r < 5; ++r) {
        float4 v4 = make_float4(0.f, 0.f, 0.f, 0.f);
        if (pidx[r] >= 0)
          v4 = *(const float4*)(key + (size_t)pidx[r] * CH + cn);
        pf[r] = v4;
      }
    }

    float4 m0 = *(const float4*)(qb0 + c0 + s4);
    float4 m1 = *(const float4*)(qb1 + c0 + s4);
#pragma unroll
    for (int i = 0; i < KS; ++i) {
      const float* sp = &s[((pr + i) * WT + qx0) * SPX + s4];
      float4 kr[6];
#pragma unroll
      for (int u = 0; u < 6; ++u) kr[u] = *(const float4*)(sp + u * SPX);
#pragma unroll
      for (int j = 0; j < KS; ++j) {
        lg0[i * 5 + j] += DOT4(m0, kr[j]);
        lg1[i * 5 + j] += DOT4(m1, kr[j + 1]);
      }
    }
  }

  // ---- cross-slice logit reduction: in-wave butterfly over lane bits 0..2
  // (slice lanes are adjacent; all 8 lanes of a pair end with the full sum)
#pragma unroll
  for (int o = 0; o < 25; ++o) {
    lg0[o] += __shfl_xor(lg0[o], 1);
    lg0[o] += __shfl_xor(lg0[o], 2);
    lg0[o] += __shfl_xor(lg0[o], 4);
    lg1[o] += __shfl_xor(lg1[o], 1);
    lg1[o] += __shfl_xor(lg1[o], 2);
    lg1[o] += __shfl_xor(lg1[o], 4);
  }

  // prefetch V chunk 0 (overlaps softmax math below)
#pragma unroll
  for (int r = 0; r < 5; ++r) {
    float4 v4 = make_float4(0.f, 0.f, 0.f, 0.f);
    if (pidx[r] >= 0)
      v4 = *(const float4*)(val + (size_t)pidx[r] * VV + s4);
    pf[r] = v4;
  }

  // ---- softmax over 25 (zero halo contributed logit 0 = TF SAME pad) ----
  {
    float mx = lg0[0];
#pragma unroll
    for (int o = 1; o < 25; ++o) mx = fmaxf(mx, lg0[o]);
    float sum = 0.f;
#pragma unroll
    for (int o = 0; o < 25; ++o) {
      lg0[o] = __expf(lg0[o] - mx);
      sum += lg0[o];
    }
    float inv = 1.f / sum;
#pragma unroll
    for (int o = 0; o < 25; ++o) lg0[o] *= inv;
  }
  {
    float mx = lg1[0];
#pragma unroll
    for (int o = 1; o < 25; ++o) mx = fmaxf(mx, lg1[o]);
    float sum = 0.f;
#pragma unroll
    for (int o = 0; o < 25; ++o) {
      lg1[o] = __expf(lg1[o] - mx);
      sum += lg1[o];
    }
    float inv = 1.f / sum;
#pragma unroll
    for (int o = 0; o < 25; ++o) lg1[o] *= inv;
  }

  // ---- Phase 2: values, V in chunks of 32; LDS-staged coalesced write ----
  for (int v0 = 0; v0 < VV; v0 += CHUNK) {
    __syncthreads(); // also covers: phase-1 tail reads done before overwrite
#pragma unroll
    for (int r = 0; r < 5; ++r)
      if (pidx[r] != -2) *(float4*)(&s[ldst[r]]) = pf[r];
    __syncthreads();
    if (v0 + CHUNK < VV) {
      int vn = v0 + CHUNK + s4;
#pragma unroll
      for (int r = 0; r < 5; ++r) {
        float4 v4 = make_float4(0.f, 0.f, 0.f, 0.f);
        if (pidx[r] >= 0)
          v4 = *(const float4*)(val + (size_t)pidx[r] * VV + vn);
        pf[r] = v4;
      }
    }

    float4 a0 = make_float4(0.f, 0.f, 0.f, 0.f);
    float4 a1 = make_float4(0.f, 0.f, 0.f, 0.f);
#pragma unroll
    for (int i = 0; i < KS; ++i) {
      const float* sp = &s[((pr + i) * WT + qx0) * SPX + s4];
      float4 vr[6];
#pragma unroll
      for (int u = 0; u < 6; ++u) vr[u] = *(const float4*)(sp + u * SPX);
#pragma unroll
      for (int j = 0; j < KS; ++j) {
        float w0a = lg0[i * 5 + j];
        float w1a = lg1[i * 5 + j];
        a0.x += w0a * vr[j].x;     a0.y += w0a * vr[j].y;
        a0.z += w0a * vr[j].z;     a0.w += w0a * vr[j].w;
        a1.x += w1a * vr[j + 1].x; a1.y += w1a * vr[j + 1].y;
        a1.z += w1a * vr[j + 1].z; a1.w += w1a * vr[j + 1].w;
      }
    }
    // stage into out-region (disjoint from halo; no barrier needed before)
    int px0 = pr * 8 + qx0;
    *(float4*)(&s[SOFF + px0 * SO + s4]) = a0;
    *(float4*)(&s[SOFF + (px0 + 1) * SO + s4]) = a1;
    __syncthreads();

    // coalesced write: 8 consecutive lanes cover 128 contiguous bytes
    for (int t = tid; t < 64 * (CHUNK / 4); t += 256) {
      int px = t >> 3, c4 = (t & 7) * 4;
      int pty = px >> 3, ptx = px & 7;
      float4 v4 = *(const float4*)(&s[SOFF + px * SO + c4]);
      *(float4*)(out + (size_t)((bb * HH + h0 + pty) * WW + w0 + ptx) * VV +
                 v0 + c4) = v4;
    }
  }
}

extern "C" void kernel_launch(void* const* d_in, const int* in_sizes, int n_in,
                              void* d_out, int out_size, void* d_ws,
                              size_t ws_size, hipStream_t stream) {
  const float* qry = (const float*)d_in[0]; // main [B,H,W,C]
  const float* key = (const float*)d_in[1]; // ref  [B,H,W,C]
  const float* val = (const float*)d_in[2]; // ref_value [B,H,W,V]
  float* out = (float*)d_out;               // [B,H,W,V]

  dim3 grid(BATCH * (HH / TH) * (WW / TW)); // 1152
  dim3 block(256);
  reflocal_kernel<<<grid, block, 0, stream>>>(qry, key, val, out);
}

// Round 3
// 189.585 us; speedup vs baseline: 2.1856x; 1.1101x over previous
//
#include <hip/hip_runtime.h>

// RefLocal: 5x5 windowed dot-product attention, fp32.
// B=8 H=96 W=96 C=192 V=96.
// R9 = R8 with staging moved to global_load_lds (async, zero-VGPR).
//  - R8 post-mortem: allocator parked at the 128-VGPR occupancy step and
//    spilled ~20 regs of the paired kernel (WRITE 42.6MB vs 27.6MB out,
//    FETCH +6.4MB) -> 103us. Fix pressure structurally: pf[5]+ldst[5]
//    (25 VGPRs) and all staging VALU replaced by
//    __builtin_amdgcn_global_load_lds (16B/lane, lane-linear LDS dst).
//  - SPX 36 -> 32 (lane-linear dst requires no pad; octet phasing of
//    ds_read_b128 makes the pad irrelevant for bank conflicts: 8 lanes of
//    a phase carry 8 distinct channel quads).
//  - OOB halo slots: masked lanes skip the LDS write, so slots are
//    pre-zeroed ONCE in both buffers and never overwritten (zero key ->
//    logit 0 = TF SAME pad; zero val -> no contribution).
//  - True double-buffer: issue chunk c+1 into buf^1 right after the
//    barrier, compute chunk c from buf; ONE barrier per chunk (vmcnt
//    drained by __syncthreads' structural waitcnt). 12 barriers vs ~21.
//  - Query-pairing kept: 2 queries x 4ch per thread, 5x6 row union read
//    once (6 b128) feeds both queries (x0.6 LDS read bytes).

#define BATCH 8
#define HH 96
#define WW 96
#define CH 192
#define VV 96
#define KS 5
#define PAD 2
#define TH 8
#define TW 8
#define HT (TH + 2 * PAD) // 12
#define WT (TW + 2 * PAD) // 12
#define NPIX (HT * WT)    // 144
#define CHUNK 32          // channels staged per iteration
#define SPX 32            // LDS floats per halo pixel (contiguous, no pad)
#define BUFSZ (NPIX * SPX) // 4608 floats = 18432 B per buffer
#define SO 36              // out-stage stride (16B-aligned float4)
#define SOFF (2 * BUFSZ)   // 9216: out-stage base (after both buffers)
#define SSZ (SOFF + 64 * SO) // 11520 floats = 46080 B

#define DOT4(m, k) \
  ((m).x * (k).x + (m).y * (k).y + (m).z * (k).z + (m).w * (k).w)

__device__ __forceinline__ void gload16(const float* g, float* l) {
  __builtin_amdgcn_global_load_lds(
      (const __attribute__((address_space(1))) float*)g,
      (__attribute__((address_space(3))) float*)l, 16, 0, 0);
}

__global__ __launch_bounds__(256, 2) void reflocal_kernel(
    const float* __restrict__ qry, const float* __restrict__ key,
    const float* __restrict__ val, float* __restrict__ out) {
  // XCD swizzle: blockIdx round-robins across 8 XCDs; one image per XCD.
  int braw = blockIdx.x;
  int L = (braw & 7) * 144 + (braw >> 3); // gridDim.x == 1152
  int bb = L / 144;
  int t2 = L - bb * 144;
  int tyy = t2 / 12;
  int txx = t2 - tyy * 12;
  int h0 = tyy * TH, w0 = txx * TW;

  int tid = threadIdx.x;
  int s4 = (tid & 7) * 4;   // 4-channel sub-slice within the 32-ch chunk
  int pr = (tid >> 3) >> 2; // query row 0..7
  int pc = (tid >> 3) & 3;  // query col-pair 0..3
  int qx0 = 2 * pc;         // first query col (halo col of window j=0)
  int wv = tid >> 6;        // wave id 0..3

  __shared__ float s[SSZ];

  // ---- per-round staging bookkeeping ----
  // round r: wave wv covers pixels [32r+8wv, 32r+8wv+8); lane l>>3 picks
  // the pixel, lane l&7 the 16B quad (HW writes LDS at base + l*16B).
  int pidx[5]; // global pixel linear index; -1 = OOB zero slot; -2 = no slot
#pragma unroll
  for (int r = 0; r < 5; ++r) {
    int px = (tid >> 3) + 32 * r;
    if (px < NPIX) {
      int ry = px / WT, rx = px - ry * WT;
      int hh = h0 - PAD + ry, ww = w0 - PAD + rx;
      pidx[r] = ((unsigned)hh < HH && (unsigned)ww < WW)
                    ? (bb * HH + hh) * WW + ww
                    : -1;
    } else {
      pidx[r] = -2;
    }
  }

  // zero OOB slots ONCE in both buffers (masked gload lanes never write)
#pragma unroll
  for (int r = 0; r < 5; ++r) {
    if (pidx[r] == -1) {
      int px = (tid >> 3) + 32 * r;
      float4 z = make_float4(0.f, 0.f, 0.f, 0.f);
      *(float4*)(&s[px * SPX + s4]) = z;
      *(float4*)(&s[BUFSZ + px * SPX + s4]) = z;
    }
  }

  float lg0[25], lg1[25];
#pragma unroll
  for (int o = 0; o < 25; ++o) { lg0[o] = 0.f; lg1[o] = 0.f; }

  const float* qb0 =
      qry + (size_t)((bb * HH + h0 + pr) * WW + w0 + qx0) * CH;
  const float* qb1 = qb0 + CH; // adjacent column pixel

  // async stage: chunk [c0,c0+32) of src (row length rl) into buf
  auto stage = [&](float* buf, const float* src, int rl, int c0) {
#pragma unroll
    for (int r = 0; r < 5; ++r) {
      int pxs = 32 * r + 8 * wv; // wave-uniform first pixel of this issue
      if (pxs < NPIX) {
        if (pidx[r] >= 0)
          gload16(src + pidx[r] * rl + c0 + s4, buf + pxs * SPX);
      }
    }
  };

  float* const bufA = (float*)s;
  float* const bufB = (float*)s + BUFSZ;

  stage(bufA, key, CH, 0); // chunk 0 in flight

  // ---- Phase 1: partial logits, C in chunks of 32 ----
  for (int ci = 0; ci < CH / CHUNK; ++ci) {
    __syncthreads(); // drains vmcnt -> cur buffer complete for all waves
    float* cur = (ci & 1) ? bufB : bufA;
    float* nxt = (ci & 1) ? bufA : bufB;
    if (ci + 1 < CH / CHUNK)
      stage(nxt, key, CH, (ci + 1) * CHUNK);
    else
      stage(nxt, val, VV, 0); // V chunk 0 hides under last K compute+softmax

    int c0 = ci * CHUNK;
    float4 m0 = *(const float4*)(qb0 + c0 + s4);
    float4 m1 = *(const float4*)(qb1 + c0 + s4);
#pragma unroll
    for (int i = 0; i < KS; ++i) {
      const float* sp = &cur[((pr + i) * WT + qx0) * SPX + s4];
      float4 kr[6];
#pragma unroll
      for (int u = 0; u < 6; ++u) kr[u] = *(const float4*)(sp + u * SPX);
#pragma unroll
      for (int j = 0; j < KS; ++j) {
        lg0[i * 5 + j] += DOT4(m0, kr[j]);
        lg1[i * 5 + j] += DOT4(m1, kr[j + 1]);
      }
    }
  }

  // ---- cross-slice logit reduction: in-wave butterfly over lane bits 0..2
#pragma unroll
  for (int o = 0; o < 25; ++o) {
    lg0[o] += __shfl_xor(lg0[o], 1);
    lg0[o] += __shfl_xor(lg0[o], 2);
    lg0[o] += __shfl_xor(lg0[o], 4);
    lg1[o] += __shfl_xor(lg1[o], 1);
    lg1[o] += __shfl_xor(lg1[o], 2);
    lg1[o] += __shfl_xor(lg1[o], 4);
  }

  // ---- softmax over 25 (zero halo contributed logit 0 = TF SAME pad) ----
  {
    float mx = lg0[0];
#pragma unroll
    for (int o = 1; o < 25; ++o) mx = fmaxf(mx, lg0[o]);
    float sum = 0.f;
#pragma unroll
    for (int o = 0; o < 25; ++o) {
      lg0[o] = __expf(lg0[o] - mx);
      sum += lg0[o];
    }
    float inv = 1.f / sum;
#pragma unroll
    for (int o = 0; o < 25; ++o) lg0[o] *= inv;
  }
  {
    float mx = lg1[0];
#pragma unroll
    for (int o = 1; o < 25; ++o) mx = fmaxf(mx, lg1[o]);
    float sum = 0.f;
#pragma unroll
    for (int o = 0; o < 25; ++o) {
      lg1[o] = __expf(lg1[o] - mx);
      sum += lg1[o];
    }
    float inv = 1.f / sum;
#pragma unroll
    for (int o = 0; o < 25; ++o) lg1[o] *= inv;
  }

  // ---- Phase 2: values, V in chunks of 32; LDS-staged coalesced write ----
  for (int vi = 0; vi < VV / CHUNK; ++vi) {
    __syncthreads(); // drains pending V-chunk loads
    float* cur = (vi & 1) ? bufB : bufA; // parity continues: V0 in bufA
    float* nxt = (vi & 1) ? bufA : bufB;
    if (vi + 1 < VV / CHUNK) stage(nxt, val, VV, (vi + 1) * CHUNK);

    float4 a0 = make_float4(0.f, 0.f, 0.f, 0.f);
    float4 a1 = make_float4(0.f, 0.f, 0.f, 0.f);
#pragma unroll
    for (int i = 0; i < KS; ++i) {
      const float* sp = &cur[((pr + i) * WT + qx0) * SPX + s4];
      float4 vr[6];
#pragma unroll
      for (int u = 0; u < 6; ++u) vr[u] = *(const float4*)(sp + u * SPX);
#pragma unroll
      for (int j = 0; j < KS; ++j) {
        float w0a = lg0[i * 5 + j];
        float w1a = lg1[i * 5 + j];
        a0.x += w0a * vr[j].x;     a0.y += w0a * vr[j].y;
        a0.z += w0a * vr[j].z;     a0.w += w0a * vr[j].w;
        a1.x += w1a * vr[j + 1].x; a1.y += w1a * vr[j + 1].y;
        a1.z += w1a * vr[j + 1].z; a1.w += w1a * vr[j + 1].w;
      }
    }
    // stage into out-region (disjoint from halo buffers)
    int px0 = pr * 8 + qx0;
    *(float4*)(&s[SOFF + px0 * SO + s4]) = a0;
    *(float4*)(&s[SOFF + (px0 + 1) * SO + s4]) = a1;
    __syncthreads();

    // coalesced write: 8 consecutive lanes cover 128 contiguous bytes
    int v0 = vi * CHUNK;
    for (int t = tid; t < 64 * (CHUNK / 4); t += 256) {
      int px = t >> 3, c4 = (t & 7) * 4;
      int pty = px >> 3, ptx = px & 7;
      float4 v4 = *(const float4*)(&s[SOFF + px * SO + c4]);
      *(float4*)(out + (size_t)((bb * HH + h0 + pty) * WW + w0 + ptx) * VV +
                 v0 + c4) = v4;
    }
  }
}

extern "C" void kernel_launch(void* const* d_in, const int* in_sizes, int n_in,
                              void* d_out, int out_size, void* d_ws,
                              size_t ws_size, hipStream_t stream) {
  const float* qry = (const float*)d_in[0]; // main [B,H,W,C]
  const float* key = (const float*)d_in[1]; // ref  [B,H,W,C]
  const float* val = (const float*)d_in[2]; // ref_value [B,H,W,V]
  float* out = (float*)d_out;               // [B,H,W,V]

  dim3 grid(BATCH * (HH / TH) * (WW / TW)); // 1152
  dim3 block(256);
  reflocal_kernel<<<grid, block, 0, stream>>>(qry, key, val, out);
}

// Round 4
// 178.538 us; speedup vs baseline: 2.3208x; 1.0619x over previous
//
#include <hip/hip_runtime.h>

// RefLocal: 5x5 windowed dot-product attention, fp32.
// B=8 H=96 W=96 C=192 V=96.
// R10 = R9 + qry register prefetch + direct output stores.
//  - R9 post-mortem: spill gone, LDS reads x0.6, conflicts x0.4, barriers
//    x0.6 vs R6 -- and IDENTICAL 81us. No pipe >~57%. Latency-exposed:
//    the per-chunk skeleton (barrier -> cold qry global loads -> dependent
//    FMA/LDS chain) is invariant across R6/R9 and sets the pace.
//  - Fix 1: m0/m1 (qry) for chunk c+1 double-buffered in registers during
//    chunk c (the only cold global load on the compute path). +8 VGPR.
//  - Fix 2: out-stage removed. Paired layout already gives 128B-contiguous
//    octet stores directly to global (same coalescing as staged path).
//    LDS 46->36.9KB (4 blocks/CU), 3 fewer barriers, ~4us/CU less LDS.
//  - Everything else identical to R9 (async global_load_lds double-buffer,
//    pre-zeroed OOB slots, query pairing, shfl_xor logit reduction).

#define BATCH 8
#define HH 96
#define WW 96
#define CH 192
#define VV 96
#define KS 5
#define PAD 2
#define TH 8
#define TW 8
#define HT (TH + 2 * PAD) // 12
#define WT (TW + 2 * PAD) // 12
#define NPIX (HT * WT)    // 144
#define CHUNK 32          // channels staged per iteration
#define SPX 32            // LDS floats per halo pixel (contiguous, no pad)
#define BUFSZ (NPIX * SPX)   // 4608 floats = 18432 B per buffer
#define SSZ (2 * BUFSZ)      // 9216 floats = 36864 B

#define DOT4(m, k) \
  ((m).x * (k).x + (m).y * (k).y + (m).z * (k).z + (m).w * (k).w)

__device__ __forceinline__ void gload16(const float* g, float* l) {
  __builtin_amdgcn_global_load_lds(
      (const __attribute__((address_space(1))) float*)g,
      (__attribute__((address_space(3))) float*)l, 16, 0, 0);
}

__global__ __launch_bounds__(256, 2) void reflocal_kernel(
    const float* __restrict__ qry, const float* __restrict__ key,
    const float* __restrict__ val, float* __restrict__ out) {
  // XCD swizzle: blockIdx round-robins across 8 XCDs; one image per XCD.
  int braw = blockIdx.x;
  int L = (braw & 7) * 144 + (braw >> 3); // gridDim.x == 1152
  int bb = L / 144;
  int t2 = L - bb * 144;
  int tyy = t2 / 12;
  int txx = t2 - tyy * 12;
  int h0 = tyy * TH, w0 = txx * TW;

  int tid = threadIdx.x;
  int s4 = (tid & 7) * 4;   // 4-channel sub-slice within the 32-ch chunk
  int pr = (tid >> 3) >> 2; // query row 0..7
  int pc = (tid >> 3) & 3;  // query col-pair 0..3
  int qx0 = 2 * pc;         // first query col (halo col of window j=0)
  int wv = tid >> 6;        // wave id 0..3

  __shared__ float s[SSZ];

  // ---- per-round staging bookkeeping ----
  // round r: wave wv covers pixels [32r+8wv, 32r+8wv+8); lane l>>3 picks
  // the pixel, lane l&7 the 16B quad (HW writes LDS at base + l*16B).
  int pidx[5]; // global pixel linear index; -1 = OOB zero slot; -2 = no slot
#pragma unroll
  for (int r = 0; r < 5; ++r) {
    int px = (tid >> 3) + 32 * r;
    if (px < NPIX) {
      int ry = px / WT, rx = px - ry * WT;
      int hh = h0 - PAD + ry, ww = w0 - PAD + rx;
      pidx[r] = ((unsigned)hh < HH && (unsigned)ww < WW)
                    ? (bb * HH + hh) * WW + ww
                    : -1;
    } else {
      pidx[r] = -2;
    }
  }

  // zero OOB slots ONCE in both buffers (masked gload lanes never write)
#pragma unroll
  for (int r = 0; r < 5; ++r) {
    if (pidx[r] == -1) {
      int px = (tid >> 3) + 32 * r;
      float4 z = make_float4(0.f, 0.f, 0.f, 0.f);
      *(float4*)(&s[px * SPX + s4]) = z;
      *(float4*)(&s[BUFSZ + px * SPX + s4]) = z;
    }
  }

  float lg0[25], lg1[25];
#pragma unroll
  for (int o = 0; o < 25; ++o) { lg0[o] = 0.f; lg1[o] = 0.f; }

  const float* qb0 =
      qry + (size_t)((bb * HH + h0 + pr) * WW + w0 + qx0) * CH;
  const float* qb1 = qb0 + CH; // adjacent column pixel

  // async stage: chunk [c0,c0+32) of src (row length rl) into buf
  auto stage = [&](float* buf, const float* src, int rl, int c0) {
#pragma unroll
    for (int r = 0; r < 5; ++r) {
      int pxs = 32 * r + 8 * wv; // wave-uniform first pixel of this issue
      if (pxs < NPIX) {
        if (pidx[r] >= 0)
          gload16(src + pidx[r] * rl + c0 + s4, buf + pxs * SPX);
      }
    }
  };

  float* const bufA = (float*)s;
  float* const bufB = (float*)s + BUFSZ;

  stage(bufA, key, CH, 0); // chunk 0 in flight

  // qry chunk-0 register prefetch
  float4 m0 = *(const float4*)(qb0 + s4);
  float4 m1 = *(const float4*)(qb1 + s4);

  // ---- Phase 1: partial logits, C in chunks of 32 ----
  for (int ci = 0; ci < CH / CHUNK; ++ci) {
    __syncthreads(); // drains vmcnt -> cur buffer complete for all waves
    float* cur = (ci & 1) ? bufB : bufA;
    float* nxt = (ci & 1) ? bufA : bufB;
    if (ci + 1 < CH / CHUNK)
      stage(nxt, key, CH, (ci + 1) * CHUNK);
    else
      stage(nxt, val, VV, 0); // V chunk 0 hides under last K compute+softmax

    // prefetch next chunk's qry into registers (lands during this compute)
    float4 mn0, mn1;
    if (ci + 1 < CH / CHUNK) {
      int cn = (ci + 1) * CHUNK + s4;
      mn0 = *(const float4*)(qb0 + cn);
      mn1 = *(const float4*)(qb1 + cn);
    }

#pragma unroll
    for (int i = 0; i < KS; ++i) {
      const float* sp = &cur[((pr + i) * WT + qx0) * SPX + s4];
      float4 kr[6];
#pragma unroll
      for (int u = 0; u < 6; ++u) kr[u] = *(const float4*)(sp + u * SPX);
#pragma unroll
      for (int j = 0; j < KS; ++j) {
        lg0[i * 5 + j] += DOT4(m0, kr[j]);
        lg1[i * 5 + j] += DOT4(m1, kr[j + 1]);
      }
    }
    m0 = mn0;
    m1 = mn1;
  }

  // ---- cross-slice logit reduction: in-wave butterfly over lane bits 0..2
#pragma unroll
  for (int o = 0; o < 25; ++o) {
    lg0[o] += __shfl_xor(lg0[o], 1);
    lg0[o] += __shfl_xor(lg0[o], 2);
    lg0[o] += __shfl_xor(lg0[o], 4);
    lg1[o] += __shfl_xor(lg1[o], 1);
    lg1[o] += __shfl_xor(lg1[o], 2);
    lg1[o] += __shfl_xor(lg1[o], 4);
  }

  // ---- softmax over 25 (zero halo contributed logit 0 = TF SAME pad) ----
  {
    float mx = lg0[0];
#pragma unroll
    for (int o = 1; o < 25; ++o) mx = fmaxf(mx, lg0[o]);
    float sum = 0.f;
#pragma unroll
    for (int o = 0; o < 25; ++o) {
      lg0[o] = __expf(lg0[o] - mx);
      sum += lg0[o];
    }
    float inv = 1.f / sum;
#pragma unroll
    for (int o = 0; o < 25; ++o) lg0[o] *= inv;
  }
  {
    float mx = lg1[0];
#pragma unroll
    for (int o = 1; o < 25; ++o) mx = fmaxf(mx, lg1[o]);
    float sum = 0.f;
#pragma unroll
    for (int o = 0; o < 25; ++o) {
      lg1[o] = __expf(lg1[o] - mx);
      sum += lg1[o];
    }
    float inv = 1.f / sum;
#pragma unroll
    for (int o = 0; o < 25; ++o) lg1[o] *= inv;
  }

  // output base pointers (query 0 / query 1 of the pair)
  float* ob0 = out + (size_t)((bb * HH + h0 + pr) * WW + w0 + qx0) * VV;
  float* ob1 = ob0 + VV;

  // ---- Phase 2: values, V in chunks of 32; direct 128B-octet stores ----
  for (int vi = 0; vi < VV / CHUNK; ++vi) {
    __syncthreads(); // drains pending V-chunk loads
    float* cur = (vi & 1) ? bufB : bufA; // parity continues: V0 in bufA
    float* nxt = (vi & 1) ? bufA : bufB;
    if (vi + 1 < VV / CHUNK) stage(nxt, val, VV, (vi + 1) * CHUNK);

    float4 a0 = make_float4(0.f, 0.f, 0.f, 0.f);
    float4 a1 = make_float4(0.f, 0.f, 0.f, 0.f);
#pragma unroll
    for (int i = 0; i < KS; ++i) {
      const float* sp = &cur[((pr + i) * WT + qx0) * SPX + s4];
      float4 vr[6];
#pragma unroll
      for (int u = 0; u < 6; ++u) vr[u] = *(const float4*)(sp + u * SPX);
#pragma unroll
      for (int j = 0; j < KS; ++j) {
        float w0a = lg0[i * 5 + j];
        float w1a = lg1[i * 5 + j];
        a0.x += w0a * vr[j].x;     a0.y += w0a * vr[j].y;
        a0.z += w0a * vr[j].z;     a0.w += w0a * vr[j].w;
        a1.x += w1a * vr[j + 1].x; a1.y += w1a * vr[j + 1].y;
        a1.z += w1a * vr[j + 1].z; a1.w += w1a * vr[j + 1].w;
      }
    }
    // direct stores: 8 lanes of an octet cover 128 contiguous bytes
    int v0 = vi * CHUNK;
    *(float4*)(ob0 + v0 + s4) = a0;
    *(float4*)(ob1 + v0 + s4) = a1;
  }
}

extern "C" void kernel_launch(void* const* d_in, const int* in_sizes, int n_in,
                              void* d_out, int out_size, void* d_ws,
                              size_t ws_size, hipStream_t stream) {
  const float* qry = (const float*)d_in[0]; // main [B,H,W,C]
  const float* key = (const float*)d_in[1]; // ref  [B,H,W,C]
  const float* val = (const float*)d_in[2]; // ref_value [B,H,W,V]
  float* out = (float*)d_out;               // [B,H,W,V]

  dim3 grid(BATCH * (HH / TH) * (WW / TW)); // 1152
  dim3 block(256);
  reflocal_kernel<<<grid, block, 0, stream>>>(qry, key, val, out);
}